// Round 6
// baseline (443.702 us; speedup 1.0000x reference)
//
#include <hip/hip_runtime.h>

// LSTM recurrence, 50 steps. B=2048, T=50, F=256, H=256, gates i,f,g,o.
// Phase 0: pack W,U (fp32) -> bf16 in MFMA-fragment order (W2, U2).
// Phase 1: xz = x@W + b for ALL timesteps (parallel GEMM), bf16 frag layout.
// Phase 2: ONE persistent kernel, 128 blocks x 16 batch rows x all 1024
//          z-cols. h double-buffered in swizzled LDS, ONE raw barrier/step
//          (lgkmcnt only -- XZ and kf5 prefetches stay in flight across it).
//          U: kf0-2 register-resident (96 VGPR), kf3-4 LDS-resident,
//          kf5-7 streamed from L2 through TWO reg buffers (VGPR demand ~236
//          so the compiler can actually keep BR0-2 resident; round-5's 3-buf
//          plan demanded ~280 -> demoted to per-step L2 reloads, VGPR=128).

#define B_ 2048
#define T_ 50
#define F_ 256
#define H_ 256
#define NZ 1024      // 4H

typedef __attribute__((ext_vector_type(8))) short short8;
typedef __attribute__((ext_vector_type(4))) float f32x4;
typedef unsigned short ushort_t;
typedef unsigned int uint_t;

__device__ __forceinline__ ushort_t f2bf(float f) {
    uint_t u = __float_as_uint(f);
    return (ushort_t)((u + 0x7FFFu + ((u >> 16) & 1u)) >> 16);
}
__device__ __forceinline__ uint_t pack2bf(float lo, float hi) {
    return (uint_t)f2bf(lo) | ((uint_t)f2bf(hi) << 16);
}
__device__ __forceinline__ float bf2f(ushort_t u) {
    return __uint_as_float(((uint_t)u) << 16);
}
__device__ __forceinline__ float sigm(float z) {
    return __builtin_amdgcn_rcpf(1.0f + __builtin_amdgcn_exp2f(z * -1.44269504f));
}
__device__ __forceinline__ float tanh_f(float z) {
    return 2.0f * __builtin_amdgcn_rcpf(1.0f + __builtin_amdgcn_exp2f(z * -2.88539008f)) - 1.0f;
}
__device__ __forceinline__ float xz_at(uint2 u, int j) {
    uint_t v = (j < 2) ? u.x : u.y;
    v = (j & 1) ? (v >> 16) : (v & 0xFFFFu);
    return bf2f((ushort_t)v);
}

// -------- pack: fp32 [256][1024] -> bf16 frag-order panels ----------------
__global__ void pack_wu(const float* __restrict__ Wm, const float* __restrict__ Um,
                        ushort_t* __restrict__ W2, ushort_t* __restrict__ U2) {
    int gid  = blockIdx.x * 256 + threadIdx.x;   // 65536 total
    int lane = gid & 63;
    int nf   = (gid >> 6) & 7;
    int w    = (gid >> 9) & 7;
    int kf   = (gid >> 12) & 7;
    int mat  = gid >> 15;
    const float* src = mat ? Um : Wm;
    ushort_t* dst    = mat ? U2 : W2;
    int col = (nf >> 1) * 256 + w * 32 + (nf & 1) * 16 + (lane & 15);
    int kb  = kf * 32 + (lane >> 4) * 8;
    short8 v;
#pragma unroll
    for (int e = 0; e < 8; ++e)
        v[e] = (short)f2bf(src[(size_t)(kb + e) * NZ + col]);
    *(short8*)(dst + ((((size_t)kf * 8 + w) * 8 + nf) * 64 + lane) * 8) = v;
}

// -------- phase 1: xz[t] = x[:,t,:] @ W + b  (bf16, frag layout) ----------
__global__ __launch_bounds__(512, 2) void xw_gemm(
    const float* __restrict__ x, const float* __restrict__ bias,
    const ushort_t* __restrict__ W2, ushort_t* __restrict__ xz2) {
    __shared__ __align__(16) ushort_t As[32 * 256];   // 16 KB, swizzled

    const int tid = threadIdx.x;
    const int t = blockIdx.x, rb = blockIdx.y, row0 = rb * 32;
    const int w = tid >> 6, lane = tid & 63, r16 = lane & 15, q = lane >> 4;

    {
        int sr = tid >> 4, sc = tid & 15;
        const float* xp = x + ((size_t)(row0 + sr) * T_ + t) * F_ + sc * 16;
        float4 f0 = *(const float4*)(xp + 0);
        float4 f1 = *(const float4*)(xp + 4);
        float4 f2 = *(const float4*)(xp + 8);
        float4 f3 = *(const float4*)(xp + 12);
        uint4 u0 = {pack2bf(f0.x, f0.y), pack2bf(f0.z, f0.w),
                    pack2bf(f1.x, f1.y), pack2bf(f1.z, f1.w)};
        uint4 u1 = {pack2bf(f2.x, f2.y), pack2bf(f2.z, f2.w),
                    pack2bf(f3.x, f3.y), pack2bf(f3.z, f3.w)};
        int c0 = (2 * sc) ^ (sr & 7), c1 = (2 * sc + 1) ^ (sr & 7);
        *(uint4*)&As[sr * 256 + c0 * 8] = u0;
        *(uint4*)&As[sr * 256 + c1 * 8] = u1;
    }
    float bcol[8];
#pragma unroll
    for (int nf = 0; nf < 8; ++nf)
        bcol[nf] = bias[(nf >> 1) * 256 + w * 32 + (nf & 1) * 16 + r16];
    __syncthreads();

    f32x4 acc0[8], acc1[8];
#pragma unroll
    for (int nf = 0; nf < 8; ++nf) {
        acc0[nf] = (f32x4){0.f, 0.f, 0.f, 0.f};
        acc1[nf] = (f32x4){0.f, 0.f, 0.f, 0.f};
    }
    short8 SB0[8], SB1[8];

#define LOADB(BUF, KF_)                                                       \
    _Pragma("unroll") for (int nf = 0; nf < 8; ++nf)                          \
        BUF[nf] = *(const short8*)(W2 +                                       \
            ((((size_t)(KF_) * 8 + w) * 8 + nf) * 64 + lane) * 8);

#define MF1(BUF, KF_)                                                         \
    do {                                                                      \
        short8 a0_ = *(const short8*)&As[r16 * 256 + (((KF_)*4 + q) ^ (r16 & 7)) * 8];       \
        short8 a1_ = *(const short8*)&As[(16 + r16) * 256 + (((KF_)*4 + q) ^ (r16 & 7)) * 8];\
        _Pragma("unroll") for (int nf = 0; nf < 8; ++nf) {                    \
            acc0[nf] = __builtin_amdgcn_mfma_f32_16x16x32_bf16(a0_, BUF[nf], acc0[nf], 0, 0, 0); \
            acc1[nf] = __builtin_amdgcn_mfma_f32_16x16x32_bf16(a1_, BUF[nf], acc1[nf], 0, 0, 0); \
        }                                                                     \
    } while (0)

    LOADB(SB0, 0); LOADB(SB1, 1);
    MF1(SB0, 0); LOADB(SB0, 2);
    MF1(SB1, 1); LOADB(SB1, 3);
    MF1(SB0, 2); LOADB(SB0, 4);
    MF1(SB1, 3); LOADB(SB1, 5);
    MF1(SB0, 4); LOADB(SB0, 6);
    MF1(SB1, 5); LOADB(SB1, 7);
    MF1(SB0, 6);
    MF1(SB1, 7);

    uint2* outp = (uint2*)xz2;
    const size_t cb = (((size_t)t * 64 + rb) * 8 + w) * 16;
#pragma unroll
    for (int m = 0; m < 2; ++m) {
#pragma unroll
        for (int nf = 0; nf < 8; ++nf) {
            f32x4 a = m ? acc1[nf] : acc0[nf];
            float b = bcol[nf];
            uint2 o = {pack2bf(a[0] + b, a[1] + b), pack2bf(a[2] + b, a[3] + b)};
            outp[(cb + m * 8 + nf) * 64 + lane] = o;
        }
    }
#undef LOADB
#undef MF1
}

// -------- phase 2: persistent recurrence, 128 blocks x 16 rows ------------
__global__ __launch_bounds__(512, 1) void lstm_rec(
    const ushort_t* __restrict__ U2, const ushort_t* __restrict__ xz2,
    float* __restrict__ outp, int T) {
    __shared__ __align__(16) ushort_t BL[65536];        // U kf3,kf4 (128 KB)
    __shared__ __align__(16) ushort_t hb[2][16 * 256];  // h dbuf (2 x 8 KB)

    const int tid = threadIdx.x;
    const int rb = blockIdx.x, row0 = rb * 16;
    const int w = tid >> 6, lane = tid & 63, r16 = lane & 15, q = lane >> 4;

    // LDS-resident kf3..kf4: linear 128 KB copy from U2 (+192 KB offset)
    {
        const char* srcb = (const char*)U2 + 3 * 65536;
#pragma unroll
        for (int i = 0; i < 16; ++i) {
            int off = i * 8192 + tid * 16;
            __builtin_amdgcn_global_load_lds(
                (const __attribute__((address_space(1))) void*)(srcb + off),
                (__attribute__((address_space(3))) void*)((char*)BL + off),
                16, 0, 0);
        }
    }
    // h0 = 0 (buffer 0 only)
    *(uint4*)&hb[0][tid * 8] = (uint4){0, 0, 0, 0};

#define LOADU(BUF, KF_)                                                       \
    _Pragma("unroll") for (int nf = 0; nf < 8; ++nf)                          \
        BUF[nf] = *(const short8*)(U2 +                                       \
            ((((size_t)(KF_) * 8 + w) * 8 + nf) * 64 + lane) * 8);

#define AFRAG(HP_, KF_)                                                       \
    (*(const short8*)&(HP_)[r16 * 256 + (((KF_)*4 + q) ^ (r16 & 7)) * 8])

#define MF8(AV_, BARR_)                                                       \
    do {                                                                      \
        short8 a_ = (AV_);                                                    \
        _Pragma("unroll") for (int nf = 0; nf < 8; ++nf)                      \
            acc[nf] = __builtin_amdgcn_mfma_f32_16x16x32_bf16(                \
                a_, (BARR_)[nf], acc[nf], 0, 0, 0);                           \
    } while (0)

#define MF8L(AV_, SEL_)                                                       \
    do {                                                                      \
        short8 a_ = (AV_);                                                    \
        _Pragma("unroll") for (int nf = 0; nf < 8; ++nf) {                    \
            short8 b_ = *(const short8*)&BL[((((SEL_)*8 + w)*8) + nf)*512 + lane*8]; \
            acc[nf] = __builtin_amdgcn_mfma_f32_16x16x32_bf16(                \
                a_, b_, acc[nf], 0, 0, 0);                                    \
        }                                                                     \
    } while (0)

    // register-resident kf0-2 (96 VGPR)
    short8 BR0[8], BR1[8], BR2[8];
    LOADU(BR0, 0); LOADU(BR1, 1); LOADU(BR2, 2);

    // two stream buffers (64 VGPR): SBa carries kf5 across the step boundary,
    // is consumed early, then refilled with kf7 within the step.
    short8 SBa[8], SBb[8];
    LOADU(SBa, 5);                       // kf5 for t=0

    const uint2* xzp = (const uint2*)xz2;
    const size_t cbconst = (((size_t)(rb >> 1)) * 8 + w) * 16 + (size_t)(rb & 1) * 8;

    f32x4 acc[8];
    f32x4 creg[2];
    creg[0] = (f32x4){0.f, 0.f, 0.f, 0.f};
    creg[1] = (f32x4){0.f, 0.f, 0.f, 0.f};

    // XZ for t=0 (single buffer; in steady state loaded one full step ahead)
    uint2 XZ[8];
#pragma unroll
    for (int k = 0; k < 8; ++k) XZ[k] = xzp[(cbconst + k) * 64 + lane];

    int cur = 0;
    __syncthreads();   // full drain once: BL + hb[0] ready

#pragma clang loop unroll(disable)
    for (int t = 0; t < T; ++t) {
        const ushort_t* hc = hb[cur];
        ushort_t* hn = hb[cur ^ 1];

        LOADU(SBb, 6);                   // kf6: ~6 MFMA clusters of cover

#pragma unroll
        for (int nf = 0; nf < 8; ++nf) acc[nf] = (f32x4){0.f, 0.f, 0.f, 0.f};

        __builtin_amdgcn_s_setprio(1);
        MF8(AFRAG(hc, 0), BR0);
        MF8(AFRAG(hc, 5), SBa);          // consume kf5 early
        __builtin_amdgcn_s_setprio(0);
        LOADU(SBa, 7);                   // kf7 into freed SBa: 5 clusters cover
        __builtin_amdgcn_s_setprio(1);
        MF8(AFRAG(hc, 1), BR1);
        MF8(AFRAG(hc, 2), BR2);
        MF8L(AFRAG(hc, 3), 0);
        MF8L(AFRAG(hc, 4), 1);
        MF8(AFRAG(hc, 6), SBb);
        MF8(AFRAG(hc, 7), SBa);
        __builtin_amdgcn_s_setprio(0);

        LOADU(SBa, 5);                   // next step's kf5: covered by epilogue+barrier

        // epilogue: gates, cell update, h -> other LDS buffer
#pragma unroll
        for (int hf = 0; hf < 2; ++hf) {
#pragma unroll
            for (int j = 0; j < 4; ++j) {
                float zi = acc[0 + hf][j] + xz_at(XZ[0 + hf], j);
                float zf = acc[2 + hf][j] + xz_at(XZ[2 + hf], j);
                float zg = acc[4 + hf][j] + xz_at(XZ[4 + hf], j);
                float zo = acc[6 + hf][j] + xz_at(XZ[6 + hf], j);
                float ig = sigm(zi);
                float fg = sigm(zf);
                float gg = tanh_f(zg);
                float og = sigm(zo);
                float cn = fg * creg[hf][j] + ig * gg;
                float hn_v = og * tanh_f(cn);
                creg[hf][j] = cn;
                int row = q * 4 + j;
                int hcol = w * 32 + hf * 16 + r16;
                int chunk = (hcol >> 3) ^ (row & 7);
                hn[row * 256 + chunk * 8 + (hcol & 7)] = f2bf(hn_v);
            }
        }

        // XZ(t+1): issued before the barrier, lands during next MFMA phase,
        // consumed in next epilogue (full-step cover). t=T-1 reads one tile
        // past the 210MB xz region -- inside the 400MiB ws, values unused.
        {
            const size_t cbn = (size_t)(t + 1) * (64 * 8 * 16) + cbconst;
#pragma unroll
            for (int k = 0; k < 8; ++k) XZ[k] = xzp[(cbn + k) * 64 + lane];
        }

        // raw barrier: drain LDS ops only; XZ/kf5 global loads stay in flight.
        asm volatile("s_waitcnt lgkmcnt(0)" ::: "memory");
        __builtin_amdgcn_s_barrier();
        cur ^= 1;
    }

    // final output: each thread reads back its OWN hb writes
#pragma unroll
    for (int hf = 0; hf < 2; ++hf) {
#pragma unroll
        for (int j = 0; j < 4; ++j) {
            int row = q * 4 + j;
            int hcol = w * 32 + hf * 16 + r16;
            int chunk = (hcol >> 3) ^ (row & 7);
            float hv = bf2f(hb[cur][row * 256 + chunk * 8 + (hcol & 7)]);
            size_t oi = (size_t)(row0 + row) * H_ + hcol;
            outp[oi] = hv;
            outp[(size_t)B_ * H_ + oi] = creg[hf][j];
        }
    }
#undef LOADU
#undef AFRAG
#undef MF8
#undef MF8L
}

extern "C" void kernel_launch(void* const* d_in, const int* in_sizes, int n_in,
                              void* d_out, int out_size, void* d_ws, size_t ws_size,
                              hipStream_t stream) {
    const float* x    = (const float*)d_in[0];
    const float* Wm   = (const float*)d_in[1];
    const float* Um   = (const float*)d_in[2];
    const float* bias = (const float*)d_in[3];

    // ws: W2 (512 KB) | U2 (512 KB) | xz2 (210 MB)   (ws_size = 400 MiB)
    ushort_t* W2  = (ushort_t*)d_ws;
    ushort_t* U2  = W2 + 262144;
    ushort_t* xz2 = U2 + 262144;

    pack_wu<<<256, 256, 0, stream>>>(Wm, Um, W2, U2);
    dim3 g1(T_, 64);
    xw_gemm<<<g1, 512, 0, stream>>>(x, bias, W2, xz2);
    lstm_rec<<<128, 512, 0, stream>>>(U2, xz2, (float*)d_out, T_);
}

// Round 7
// 340.921 us; speedup vs baseline: 1.3015x; 1.3015x over previous
//
#include <hip/hip_runtime.h>

// LSTM recurrence, 50 steps. B=2048, T=50, F=256, H=256, gates i,f,g,o.
// Phase 0: pack W,U (fp32) -> bf16 in MFMA-fragment order (W2, U2).
// Phase 1: xz = x@W + b for ALL timesteps (parallel GEMM), bf16 frag layout.
// Phase 2: ONE persistent kernel, 128 blocks x 16 batch rows x all 1024
//          z-cols. FULL U residency: kf0-5 pinned in registers (asm pin
//          defeats rematerialization -- rounds 5/6 came back VGPR=128 because
//          the compiler sank the loads into the loop), kf6-7 in LDS, h dbuf
//          in LDS. Per-step VMEM = ONLY the xz prefetch -> no in-order vmcnt
//          gating (the round-4..6 stall: HBM xz issued before L2 U loads
//          serialized one HBM latency into every step). Two-pass hf-split
//          MFMA+epilogue fits the 256-VGPR budget.

#define B_ 2048
#define T_ 50
#define F_ 256
#define H_ 256
#define NZ 1024      // 4H

typedef __attribute__((ext_vector_type(8))) short short8;
typedef __attribute__((ext_vector_type(4))) float f32x4;
typedef unsigned short ushort_t;
typedef unsigned int uint_t;

__device__ __forceinline__ ushort_t f2bf(float f) {
    uint_t u = __float_as_uint(f);
    return (ushort_t)((u + 0x7FFFu + ((u >> 16) & 1u)) >> 16);
}
__device__ __forceinline__ uint_t pack2bf(float lo, float hi) {
    return (uint_t)f2bf(lo) | ((uint_t)f2bf(hi) << 16);
}
__device__ __forceinline__ float bf2f(ushort_t u) {
    return __uint_as_float(((uint_t)u) << 16);
}
__device__ __forceinline__ float sigm(float z) {
    return __builtin_amdgcn_rcpf(1.0f + __builtin_amdgcn_exp2f(z * -1.44269504f));
}
__device__ __forceinline__ float tanh_f(float z) {
    return 2.0f * __builtin_amdgcn_rcpf(1.0f + __builtin_amdgcn_exp2f(z * -2.88539008f)) - 1.0f;
}
__device__ __forceinline__ float xz_at(uint2 u, int j) {
    uint_t v = (j < 2) ? u.x : u.y;
    v = (j & 1) ? (v >> 16) : (v & 0xFFFFu);
    return bf2f((ushort_t)v);
}

// -------- pack: fp32 [256][1024] -> bf16 frag-order panels ----------------
__global__ void pack_wu(const float* __restrict__ Wm, const float* __restrict__ Um,
                        ushort_t* __restrict__ W2, ushort_t* __restrict__ U2) {
    int gid  = blockIdx.x * 256 + threadIdx.x;   // 65536 total
    int lane = gid & 63;
    int nf   = (gid >> 6) & 7;
    int w    = (gid >> 9) & 7;
    int kf   = (gid >> 12) & 7;
    int mat  = gid >> 15;
    const float* src = mat ? Um : Wm;
    ushort_t* dst    = mat ? U2 : W2;
    int col = (nf >> 1) * 256 + w * 32 + (nf & 1) * 16 + (lane & 15);
    int kb  = kf * 32 + (lane >> 4) * 8;
    short8 v;
#pragma unroll
    for (int e = 0; e < 8; ++e)
        v[e] = (short)f2bf(src[(size_t)(kb + e) * NZ + col]);
    *(short8*)(dst + ((((size_t)kf * 8 + w) * 8 + nf) * 64 + lane) * 8) = v;
}

// -------- phase 1: xz[t] = x[:,t,:] @ W + b  (bf16, frag layout) ----------
__global__ __launch_bounds__(512, 2) void xw_gemm(
    const float* __restrict__ x, const float* __restrict__ bias,
    const ushort_t* __restrict__ W2, ushort_t* __restrict__ xz2) {
    __shared__ __align__(16) ushort_t As[32 * 256];   // 16 KB, swizzled

    const int tid = threadIdx.x;
    const int t = blockIdx.x, rb = blockIdx.y, row0 = rb * 32;
    const int w = tid >> 6, lane = tid & 63, r16 = lane & 15, q = lane >> 4;

    {
        int sr = tid >> 4, sc = tid & 15;
        const float* xp = x + ((size_t)(row0 + sr) * T_ + t) * F_ + sc * 16;
        float4 f0 = *(const float4*)(xp + 0);
        float4 f1 = *(const float4*)(xp + 4);
        float4 f2 = *(const float4*)(xp + 8);
        float4 f3 = *(const float4*)(xp + 12);
        uint4 u0 = {pack2bf(f0.x, f0.y), pack2bf(f0.z, f0.w),
                    pack2bf(f1.x, f1.y), pack2bf(f1.z, f1.w)};
        uint4 u1 = {pack2bf(f2.x, f2.y), pack2bf(f2.z, f2.w),
                    pack2bf(f3.x, f3.y), pack2bf(f3.z, f3.w)};
        int c0 = (2 * sc) ^ (sr & 7), c1 = (2 * sc + 1) ^ (sr & 7);
        *(uint4*)&As[sr * 256 + c0 * 8] = u0;
        *(uint4*)&As[sr * 256 + c1 * 8] = u1;
    }
    float bcol[8];
#pragma unroll
    for (int nf = 0; nf < 8; ++nf)
        bcol[nf] = bias[(nf >> 1) * 256 + w * 32 + (nf & 1) * 16 + r16];
    __syncthreads();

    f32x4 acc0[8], acc1[8];
#pragma unroll
    for (int nf = 0; nf < 8; ++nf) {
        acc0[nf] = (f32x4){0.f, 0.f, 0.f, 0.f};
        acc1[nf] = (f32x4){0.f, 0.f, 0.f, 0.f};
    }
    short8 SB0[8], SB1[8];

#define LOADB(BUF, KF_)                                                       \
    _Pragma("unroll") for (int nf = 0; nf < 8; ++nf)                          \
        BUF[nf] = *(const short8*)(W2 +                                       \
            ((((size_t)(KF_) * 8 + w) * 8 + nf) * 64 + lane) * 8);

#define MF1(BUF, KF_)                                                         \
    do {                                                                      \
        short8 a0_ = *(const short8*)&As[r16 * 256 + (((KF_)*4 + q) ^ (r16 & 7)) * 8];       \
        short8 a1_ = *(const short8*)&As[(16 + r16) * 256 + (((KF_)*4 + q) ^ (r16 & 7)) * 8];\
        _Pragma("unroll") for (int nf = 0; nf < 8; ++nf) {                    \
            acc0[nf] = __builtin_amdgcn_mfma_f32_16x16x32_bf16(a0_, BUF[nf], acc0[nf], 0, 0, 0); \
            acc1[nf] = __builtin_amdgcn_mfma_f32_16x16x32_bf16(a1_, BUF[nf], acc1[nf], 0, 0, 0); \
        }                                                                     \
    } while (0)

    LOADB(SB0, 0); LOADB(SB1, 1);
    MF1(SB0, 0); LOADB(SB0, 2);
    MF1(SB1, 1); LOADB(SB1, 3);
    MF1(SB0, 2); LOADB(SB0, 4);
    MF1(SB1, 3); LOADB(SB1, 5);
    MF1(SB0, 4); LOADB(SB0, 6);
    MF1(SB1, 5); LOADB(SB1, 7);
    MF1(SB0, 6);
    MF1(SB1, 7);

    uint2* outp = (uint2*)xz2;
    const size_t cb = (((size_t)t * 64 + rb) * 8 + w) * 16;
#pragma unroll
    for (int m = 0; m < 2; ++m) {
#pragma unroll
        for (int nf = 0; nf < 8; ++nf) {
            f32x4 a = m ? acc1[nf] : acc0[nf];
            float b = bcol[nf];
            uint2 o = {pack2bf(a[0] + b, a[1] + b), pack2bf(a[2] + b, a[3] + b)};
            outp[(cb + m * 8 + nf) * 64 + lane] = o;
        }
    }
#undef LOADB
#undef MF1
}

// -------- phase 2: persistent recurrence, 128 blocks x 16 rows ------------
__global__ __launch_bounds__(512, 2) void lstm_rec(
    const ushort_t* __restrict__ U2, const ushort_t* __restrict__ xz2,
    float* __restrict__ outp, int T) {
    __shared__ __align__(16) ushort_t BL[65536];        // U kf6,kf7 (128 KB)
    __shared__ __align__(16) ushort_t hb[2][16 * 256];  // h dbuf (2 x 8 KB)

    const int tid = threadIdx.x;
    const int rb = blockIdx.x, row0 = rb * 16;
    const int w = tid >> 6, lane = tid & 63, r16 = lane & 15, q = lane >> 4;

    // LDS-resident kf6..kf7: linear 128 KB copy from U2 (+384 KB offset)
    {
        const char* srcb = (const char*)U2 + 6 * 65536;
#pragma unroll
        for (int i = 0; i < 16; ++i) {
            int off = i * 8192 + tid * 16;
            __builtin_amdgcn_global_load_lds(
                (const __attribute__((address_space(1))) void*)(srcb + off),
                (__attribute__((address_space(3))) void*)((char*)BL + off),
                16, 0, 0);
        }
    }
    // h0 = 0 (buffer 0 only)
    *(uint4*)&hb[0][tid * 8] = (uint4){0, 0, 0, 0};

#define LOADU(BUF, KF_)                                                       \
    _Pragma("unroll") for (int nf = 0; nf < 8; ++nf)                          \
        BUF[nf] = *(const short8*)(U2 +                                       \
            ((((size_t)(KF_) * 8 + w) * 8 + nf) * 64 + lane) * 8);

#define PIN8(ARR)                                                             \
    do { _Pragma("unroll") for (int i_ = 0; i_ < 8; ++i_)                     \
        asm volatile("" : "+v"((ARR)[i_])); } while (0)

#define AFRAG(HP_, KF_)                                                       \
    (*(const short8*)&(HP_)[r16 * 256 + (((KF_)*4 + q) ^ (r16 & 7)) * 8])

    // 4 MFMAs of one parity (P_=hf) against a register panel
#define MF4(AV_, BARR_, P_)                                                   \
    do {                                                                      \
        short8 a_ = (AV_);                                                    \
        _Pragma("unroll") for (int g_ = 0; g_ < 4; ++g_)                      \
            acc[g_] = __builtin_amdgcn_mfma_f32_16x16x32_bf16(                \
                a_, (BARR_)[2 * g_ + (P_)], acc[g_], 0, 0, 0);                \
    } while (0)

    // 4 MFMAs of one parity against an LDS panel (sel 0/1 = kf6/kf7)
#define MF4L(AV_, SEL_, P_)                                                   \
    do {                                                                      \
        short8 a_ = (AV_);                                                    \
        _Pragma("unroll") for (int g_ = 0; g_ < 4; ++g_) {                    \
            short8 b_ = *(const short8*)&BL[((((SEL_)*8 + w)*8) +             \
                                             (2*g_ + (P_)))*512 + lane*8];    \
            acc[g_] = __builtin_amdgcn_mfma_f32_16x16x32_bf16(                \
                a_, b_, acc[g_], 0, 0, 0);                                    \
        }                                                                     \
    } while (0)

    // full-resident register panels kf0-5 (192 VGPR), pinned against remat
    short8 BR0[8], BR1[8], BR2[8], BR3[8], BR4[8], BR5[8];
    LOADU(BR0, 0); LOADU(BR1, 1); LOADU(BR2, 2);
    LOADU(BR3, 3); LOADU(BR4, 4); LOADU(BR5, 5);
    PIN8(BR0); PIN8(BR1); PIN8(BR2); PIN8(BR3); PIN8(BR4); PIN8(BR5);

    const uint2* xzp = (const uint2*)xz2;
    // base for this (block, wave); frag k=nf at xzb[t*8192*... ]:
    const size_t cbconst = (((size_t)(rb >> 1)) * 8 + w) * 16 + (size_t)(rb & 1) * 8;
    const uint2* xzb = xzp + cbconst * 64 + lane;
    // per-t stride in uint2 elements: 64*8*16*64 = 655360... careful:
    // element index = (t*8192 + cbconst + k)*64 + lane -> stride t: 8192*64
    const size_t TSTRIDE = (size_t)8192 * 64;

    f32x4 acc[4];
    f32x4 creg[2];
    creg[0] = (f32x4){0.f, 0.f, 0.f, 0.f};
    creg[1] = (f32x4){0.f, 0.f, 0.f, 0.f};

    // XZ for t=0, split by parity (pass A = even nf, pass B = odd nf)
    uint2 XZA[4], XZB[4];
#pragma unroll
    for (int g = 0; g < 4; ++g) XZA[g] = xzb[(size_t)(2 * g) * 64];
#pragma unroll
    for (int g = 0; g < 4; ++g) XZB[g] = xzb[(size_t)(2 * g + 1) * 64];

    int cur = 0;
    __syncthreads();   // full drain once: BL + hb[0] + BR loads ready

#pragma clang loop unroll(disable)
    for (int t = 0; t < T; ++t) {
        const ushort_t* hc = hb[cur];
        ushort_t* hn = hb[cur ^ 1];
        const uint2* xznext = xzb + (size_t)(t + 1) * TSTRIDE;

        // ================= PASS A (hf = 0, even nf) =================
#pragma unroll
        for (int g = 0; g < 4; ++g) acc[g] = (f32x4){0.f, 0.f, 0.f, 0.f};

        __builtin_amdgcn_s_setprio(1);
        MF4(AFRAG(hc, 0), BR0, 0);
        MF4(AFRAG(hc, 1), BR1, 0);
        MF4(AFRAG(hc, 2), BR2, 0);
        MF4(AFRAG(hc, 3), BR3, 0);
        MF4(AFRAG(hc, 4), BR4, 0);
        MF4(AFRAG(hc, 5), BR5, 0);
        MF4L(AFRAG(hc, 6), 0, 0);
        MF4L(AFRAG(hc, 7), 1, 0);
        __builtin_amdgcn_s_setprio(0);

        // epilogue A: gates for hf=0 cols (consumes XZA(t))
#pragma unroll
        for (int j = 0; j < 4; ++j) {
            float zi = acc[0][j] + xz_at(XZA[0], j);
            float zf = acc[1][j] + xz_at(XZA[1], j);
            float zg = acc[2][j] + xz_at(XZA[2], j);
            float zo = acc[3][j] + xz_at(XZA[3], j);
            float ig = sigm(zi);
            float fg = sigm(zf);
            float gg = tanh_f(zg);
            float og = sigm(zo);
            float cn = fg * creg[0][j] + ig * gg;
            float hv = og * tanh_f(cn);
            creg[0][j] = cn;
            int row = q * 4 + j;
            int hcol = w * 32 + r16;                    // hf=0
            int chunk = (hcol >> 3) ^ (row & 7);
            hn[row * 256 + chunk * 8 + (hcol & 7)] = f2bf(hv);
        }
        // refill XZA with t+1 (covered by pass B + barrier + next pass A)
#pragma unroll
        for (int g = 0; g < 4; ++g) XZA[g] = xznext[(size_t)(2 * g) * 64];

        // ================= PASS B (hf = 1, odd nf) ==================
#pragma unroll
        for (int g = 0; g < 4; ++g) acc[g] = (f32x4){0.f, 0.f, 0.f, 0.f};

        __builtin_amdgcn_s_setprio(1);
        MF4(AFRAG(hc, 0), BR0, 1);
        MF4(AFRAG(hc, 1), BR1, 1);
        MF4(AFRAG(hc, 2), BR2, 1);
        MF4(AFRAG(hc, 3), BR3, 1);
        MF4(AFRAG(hc, 4), BR4, 1);
        MF4(AFRAG(hc, 5), BR5, 1);
        MF4L(AFRAG(hc, 6), 0, 1);
        MF4L(AFRAG(hc, 7), 1, 1);
        __builtin_amdgcn_s_setprio(0);

        // epilogue B: gates for hf=1 cols (consumes XZB(t))
#pragma unroll
        for (int j = 0; j < 4; ++j) {
            float zi = acc[0][j] + xz_at(XZB[0], j);
            float zf = acc[1][j] + xz_at(XZB[1], j);
            float zg = acc[2][j] + xz_at(XZB[2], j);
            float zo = acc[3][j] + xz_at(XZB[3], j);
            float ig = sigm(zi);
            float fg = sigm(zf);
            float gg = tanh_f(zg);
            float og = sigm(zo);
            float cn = fg * creg[1][j] + ig * gg;
            float hv = og * tanh_f(cn);
            creg[1][j] = cn;
            int row = q * 4 + j;
            int hcol = w * 32 + 16 + r16;               // hf=1
            int chunk = (hcol >> 3) ^ (row & 7);
            hn[row * 256 + chunk * 8 + (hcol & 7)] = f2bf(hv);
        }
        // refill XZB with t+1 (t=T-1 reads one tile past xz -- inside ws,
        // values unused)
#pragma unroll
        for (int g = 0; g < 4; ++g) XZB[g] = xznext[(size_t)(2 * g + 1) * 64];

        // raw barrier: drain LDS writes only; XZ prefetch stays in flight.
        asm volatile("s_waitcnt lgkmcnt(0)" ::: "memory");
        __builtin_amdgcn_s_barrier();
        cur ^= 1;
    }

    // final output: each thread reads back its OWN hb writes
#pragma unroll
    for (int hf = 0; hf < 2; ++hf) {
#pragma unroll
        for (int j = 0; j < 4; ++j) {
            int row = q * 4 + j;
            int hcol = w * 32 + hf * 16 + r16;
            int chunk = (hcol >> 3) ^ (row & 7);
            float hv = bf2f(hb[cur][row * 256 + chunk * 8 + (hcol & 7)]);
            size_t oi = (size_t)(row0 + row) * H_ + hcol;
            outp[oi] = hv;
            outp[(size_t)B_ * H_ + oi] = creg[hf][j];
        }
    }
#undef LOADU
#undef PIN8
#undef AFRAG
#undef MF4
#undef MF4L
}

extern "C" void kernel_launch(void* const* d_in, const int* in_sizes, int n_in,
                              void* d_out, int out_size, void* d_ws, size_t ws_size,
                              hipStream_t stream) {
    const float* x    = (const float*)d_in[0];
    const float* Wm   = (const float*)d_in[1];
    const float* Um   = (const float*)d_in[2];
    const float* bias = (const float*)d_in[3];

    // ws: W2 (512 KB) | U2 (512 KB) | xz2 (210 MB)   (ws_size = 400 MiB)
    ushort_t* W2  = (ushort_t*)d_ws;
    ushort_t* U2  = W2 + 262144;
    ushort_t* xz2 = U2 + 262144;

    pack_wu<<<256, 256, 0, stream>>>(Wm, Um, W2, U2);
    dim3 g1(T_, 64);
    xw_gemm<<<g1, 512, 0, stream>>>(x, bias, W2, xz2);
    lstm_rec<<<128, 512, 0, stream>>>(U2, xz2, (float*)d_out, T_);
}